// Round 1
// baseline (573.569 us; speedup 1.0000x reference)
//
#include <hip/hip_runtime.h>

#define L 1600
#define C 256
#define HW 40
#define HP 56            // padded spatial (40 + 2*8)
#define HP2 (HP * HP)    // 3136
#define KW 17
#define K2 289
#define HEADS 8
#define C1 32
#define SCALE 0.17677669529663687f  // 32^-0.5

// workspace layout (in floats)
#define OFF_Q 0
#define OFF_K 409600
#define OFF_V (409600 + 802816)
#define OFF_A (409600 + 2 * 802816)

__global__ __launch_bounds__(256) void zero_kernel(float4* __restrict__ p, int n4) {
    int i = blockIdx.x * 256 + threadIdx.x;
    if (i < n4) p[i] = make_float4(0.f, 0.f, 0.f, 0.f);
}

// qkv[l, oc] = sum_c x[c, l] * w[oc, c] + b[oc];  q scaled, k/v scattered into padded images
__global__ __launch_bounds__(256) void qkv_gemm(const float* __restrict__ x,
                                                const float* __restrict__ w,
                                                const float* __restrict__ bias,
                                                float* __restrict__ qbuf,
                                                float* __restrict__ kpad,
                                                float* __restrict__ vpad) {
    __shared__ float As[16][68];  // A[c][l]
    __shared__ float Bs[16][68];  // B[c][oc]
    const int l0 = blockIdx.x * 64;
    const int oc0 = blockIdx.y * 64;
    const int tid = threadIdx.x;
    const int tx = tid & 15;   // oc quad
    const int ty = tid >> 4;   // l quad
    float acc[4][4] = {};
    for (int c0 = 0; c0 < C; c0 += 16) {
#pragma unroll
        for (int i = 0; i < 4; ++i) {
            int idx = i * 256 + tid;
            int cc = idx >> 6, ll = idx & 63;
            As[cc][ll] = x[(c0 + cc) * L + l0 + ll];
        }
#pragma unroll
        for (int i = 0; i < 4; ++i) {
            int idx = i * 256 + tid;
            int cc = idx & 15, oo = idx >> 4;
            Bs[cc][oo] = w[(oc0 + oo) * C + c0 + cc];
        }
        __syncthreads();
#pragma unroll
        for (int kk = 0; kk < 16; ++kk) {
            float4 a = *(const float4*)&As[kk][ty * 4];
            float4 b = *(const float4*)&Bs[kk][tx * 4];
            float av[4] = {a.x, a.y, a.z, a.w};
            float bv[4] = {b.x, b.y, b.z, b.w};
#pragma unroll
            for (int i = 0; i < 4; ++i)
#pragma unroll
                for (int j = 0; j < 4; ++j)
                    acc[i][j] = fmaf(av[i], bv[j], acc[i][j]);
        }
        __syncthreads();
    }
    const int lbase = l0 + ty * 4;
    const int ocbase = oc0 + tx * 4;
    if (oc0 < 256) {
#pragma unroll
        for (int i = 0; i < 4; ++i) {
            float4 v;
            v.x = (acc[i][0] + bias[ocbase + 0]) * SCALE;
            v.y = (acc[i][1] + bias[ocbase + 1]) * SCALE;
            v.z = (acc[i][2] + bias[ocbase + 2]) * SCALE;
            v.w = (acc[i][3] + bias[ocbase + 3]) * SCALE;
            *(float4*)&qbuf[(lbase + i) * C + ocbase] = v;
        }
    } else {
        float* dst = (oc0 < 512) ? kpad : vpad;
        const int cb = ocbase - ((oc0 < 512) ? 256 : 512);
#pragma unroll
        for (int i = 0; i < 4; ++i) {
            int l = lbase + i;
            int r = l / HW, s = l % HW;
            int base = (r + 8) * HP + (s + 8);
#pragma unroll
            for (int j = 0; j < 4; ++j)
                dst[(cb + j) * HP2 + base] = acc[i][j] + bias[ocbase + j];
        }
    }
}

// one block per spatial position n; scrambled-window attention
__global__ __launch_bounds__(256) void attn_kernel(const float* __restrict__ qbuf,
                                                   const float* __restrict__ kpad,
                                                   const float* __restrict__ vpad,
                                                   float* __restrict__ abuf) {
    __shared__ float qs[C];
    __shared__ float logit[HEADS][292];
    __shared__ int woff[K2];
    const int n = blockIdx.x;
    const int tid = threadIdx.x;
    const int nr = n / HW, ncl = n % HW;
    const int basen = nr * HP + ncl;  // top-left of window in padded coords

    qs[tid] = qbuf[n * C + tid];
    for (int p = tid; p < K2; p += 256) woff[p] = (p / KW) * HP + (p % KW);
    __syncthreads();

    // phase B: logits for all (h, n1) pairs; pair = n1*8 + h so h is fixed per thread
    {
        const int h0 = tid & 7;
        float qreg[C1];
#pragma unroll
        for (int cc = 0; cc < C1; ++cc) qreg[cc] = qs[h0 * C1 + cc];
        const float* kb = kpad + basen;
        for (int pair = tid; pair < HEADS * K2; pair += 256) {
            const int n1 = pair >> 3;
            int j = n1 * 256 + h0 * 32;
            int c = j / 289;
            int p = j - c * 289;
            float acc = 0.f;
#pragma unroll
            for (int cc = 0; cc < C1; ++cc) {
                acc = fmaf(qreg[cc], kb[c * HP2 + woff[p]], acc);
                if (++p == 289) { p = 0; ++c; }
            }
            logit[h0][n1] = acc;
        }
    }
    __syncthreads();

    // phase C: softmax over n1 per head, then post-softmax validity mask
    {
        const int wave = tid >> 6, lane = tid & 63;
        for (int hh = wave * 2; hh <= wave * 2 + 1; ++hh) {
            float mx = -1e30f;
            for (int n1 = lane; n1 < K2; n1 += 64) mx = fmaxf(mx, logit[hh][n1]);
#pragma unroll
            for (int off = 32; off; off >>= 1) mx = fmaxf(mx, __shfl_xor(mx, off, 64));
            float s = 0.f;
            for (int n1 = lane; n1 < K2; n1 += 64) {
                float e = __expf(logit[hh][n1] - mx);
                logit[hh][n1] = e;
                s += e;
            }
#pragma unroll
            for (int off = 32; off; off >>= 1) s += __shfl_xor(s, off, 64);
            const float inv = 1.f / s;
            for (int n1 = lane; n1 < K2; n1 += 64) {
                int dr = n1 / KW, ds = n1 % KW;
                int rr = nr + dr - 8, ss = ncl + ds - 8;
                float m = (rr >= 0 && rr < HW && ss >= 0 && ss < HW) ? 1.f : 0.f;
                logit[hh][n1] *= inv * m;
            }
        }
    }
    __syncthreads();

    // phase D: PV.  thread tid = h*32 + cc computes out2[n, tid]
    {
        const int h = tid >> 5;
        int p = tid & 255;  // j0 = h*32+cc = tid < 256 < 289 -> c=0, p=j0
        int c = 0;
        const float* vb = vpad + basen;
        float acc = 0.f;
        for (int n1 = 0; n1 < K2; ++n1) {
            acc = fmaf(logit[h][n1], vb[c * HP2 + woff[p]], acc);
            p += 256;
            if (p >= 289) { p -= 289; ++c; }
        }
        abuf[n * C + tid] = acc;
    }
}

// out[oc*1600 + l] = sum_c abuf[l, c] * w[oc, c] + b[oc]   (transposed store)
__global__ __launch_bounds__(256) void proj_gemm(const float* __restrict__ abuf,
                                                 const float* __restrict__ w,
                                                 const float* __restrict__ bias,
                                                 float* __restrict__ out) {
    __shared__ float As[16][68];  // A[c][l]
    __shared__ float Bs[16][68];  // B[c][oc]
    const int l0 = blockIdx.x * 64;
    const int oc0 = blockIdx.y * 64;
    const int tid = threadIdx.x;
    const int tx = tid & 15;   // l quad
    const int ty = tid >> 4;   // oc quad
    float acc[4][4] = {};      // [i: oc][j: l]
    for (int c0 = 0; c0 < C; c0 += 16) {
#pragma unroll
        for (int i = 0; i < 4; ++i) {
            int idx = i * 256 + tid;
            int cc = idx & 15, ll = idx >> 4;
            As[cc][ll] = abuf[(l0 + ll) * C + c0 + cc];
        }
#pragma unroll
        for (int i = 0; i < 4; ++i) {
            int idx = i * 256 + tid;
            int cc = idx & 15, oo = idx >> 4;
            Bs[cc][oo] = w[(oc0 + oo) * C + c0 + cc];
        }
        __syncthreads();
#pragma unroll
        for (int kk = 0; kk < 16; ++kk) {
            float4 a = *(const float4*)&As[kk][tx * 4];
            float4 b = *(const float4*)&Bs[kk][ty * 4];
            float av[4] = {a.x, a.y, a.z, a.w};
            float bv[4] = {b.x, b.y, b.z, b.w};
#pragma unroll
            for (int i = 0; i < 4; ++i)
#pragma unroll
                for (int j = 0; j < 4; ++j)
                    acc[i][j] = fmaf(bv[i], av[j], acc[i][j]);
        }
        __syncthreads();
    }
    const int lb = l0 + tx * 4;
#pragma unroll
    for (int i = 0; i < 4; ++i) {
        int oc = oc0 + ty * 4 + i;
        float bp = bias[oc];
        float4 v = make_float4(acc[i][0] + bp, acc[i][1] + bp,
                               acc[i][2] + bp, acc[i][3] + bp);
        *(float4*)&out[oc * L + lb] = v;
    }
}

extern "C" void kernel_launch(void* const* d_in, const int* in_sizes, int n_in,
                              void* d_out, int out_size, void* d_ws, size_t ws_size,
                              hipStream_t stream) {
    const float* x      = (const float*)d_in[0];
    const float* w_qkv  = (const float*)d_in[1];
    const float* b_qkv  = (const float*)d_in[2];
    const float* w_proj = (const float*)d_in[3];
    const float* b_proj = (const float*)d_in[4];
    float* out = (float*)d_out;
    float* ws = (float*)d_ws;
    float* qbuf = ws + OFF_Q;
    float* kpad = ws + OFF_K;
    float* vpad = ws + OFF_V;
    float* abuf = ws + OFF_A;

    // zero padded K/V images (both contiguous: 2 * 802816 floats)
    const int n4 = (2 * 802816) / 4;
    zero_kernel<<<n4 / 256, 256, 0, stream>>>((float4*)kpad, n4);

    qkv_gemm<<<dim3(25, 12), 256, 0, stream>>>(x, w_qkv, b_qkv, qbuf, kpad, vpad);
    attn_kernel<<<1600, 256, 0, stream>>>(qbuf, kpad, vpad, abuf);
    proj_gemm<<<dim3(25, 4), 256, 0, stream>>>(abuf, w_proj, b_proj, out);
}

// Round 2
// 302.744 us; speedup vs baseline: 1.8946x; 1.8946x over previous
//
#include <hip/hip_runtime.h>

#define L 1600
#define C 256
#define HW 40
#define HP 56            // padded spatial (40 + 2*8)
#define HP2 (HP * HP)    // 3136
#define KW 17
#define K2 289
#define HEADS 8
#define C1 32
#define NJ (K2 * C)      // 73984 flat window elements
#define SCALE 0.17677669529663687f  // 32^-0.5

// workspace layout (in floats)
#define OFF_Q 0
#define OFF_K 409600
#define OFF_V (409600 + 802816)
#define OFF_A (409600 + 2 * 802816)
#define OFF_T (409600 + 2 * 802816 + 409600)

__global__ __launch_bounds__(256) void zero_kernel(float4* __restrict__ p, int n4) {
    int i = blockIdx.x * 256 + threadIdx.x;
    if (i < n4) p[i] = make_float4(0.f, 0.f, 0.f, 0.f);
}

// addrtab[j] = offset of flat-window element j within the padded image (relative
// to the window's top-left corner). j = c*289 + p, p = dr*17 + ds.
__global__ __launch_bounds__(256) void addr_kernel(int* __restrict__ addrtab) {
    int j = blockIdx.x * 256 + threadIdx.x;   // grid sized exactly NJ
    int c = j / K2;
    int p = j - c * K2;
    int dr = p / KW;
    int ds = p - dr * KW;
    addrtab[j] = c * HP2 + dr * HP + ds;
}

// qkv[l, oc] = sum_c x[c, l] * w[oc, c] + b[oc];  q scaled, k/v scattered into padded images
__global__ __launch_bounds__(256) void qkv_gemm(const float* __restrict__ x,
                                                const float* __restrict__ w,
                                                const float* __restrict__ bias,
                                                float* __restrict__ qbuf,
                                                float* __restrict__ kpad,
                                                float* __restrict__ vpad) {
    __shared__ float As[16][68];  // A[c][l]
    __shared__ float Bs[16][68];  // B[c][oc]
    const int l0 = blockIdx.x * 64;
    const int oc0 = blockIdx.y * 64;
    const int tid = threadIdx.x;
    const int tx = tid & 15;   // oc quad
    const int ty = tid >> 4;   // l quad
    float acc[4][4] = {};
    for (int c0 = 0; c0 < C; c0 += 16) {
#pragma unroll
        for (int i = 0; i < 4; ++i) {
            int idx = i * 256 + tid;
            int cc = idx >> 6, ll = idx & 63;
            As[cc][ll] = x[(c0 + cc) * L + l0 + ll];
        }
#pragma unroll
        for (int i = 0; i < 4; ++i) {
            int idx = i * 256 + tid;
            int cc = idx & 15, oo = idx >> 4;
            Bs[cc][oo] = w[(oc0 + oo) * C + c0 + cc];
        }
        __syncthreads();
#pragma unroll
        for (int kk = 0; kk < 16; ++kk) {
            float4 a = *(const float4*)&As[kk][ty * 4];
            float4 b = *(const float4*)&Bs[kk][tx * 4];
            float av[4] = {a.x, a.y, a.z, a.w};
            float bv[4] = {b.x, b.y, b.z, b.w};
#pragma unroll
            for (int i = 0; i < 4; ++i)
#pragma unroll
                for (int j = 0; j < 4; ++j)
                    acc[i][j] = fmaf(av[i], bv[j], acc[i][j]);
        }
        __syncthreads();
    }
    const int lbase = l0 + ty * 4;
    const int ocbase = oc0 + tx * 4;
    if (oc0 < 256) {
#pragma unroll
        for (int i = 0; i < 4; ++i) {
            float4 v;
            v.x = (acc[i][0] + bias[ocbase + 0]) * SCALE;
            v.y = (acc[i][1] + bias[ocbase + 1]) * SCALE;
            v.z = (acc[i][2] + bias[ocbase + 2]) * SCALE;
            v.w = (acc[i][3] + bias[ocbase + 3]) * SCALE;
            *(float4*)&qbuf[(lbase + i) * C + ocbase] = v;
        }
    } else {
        float* dst = (oc0 < 512) ? kpad : vpad;
        const int cb = ocbase - ((oc0 < 512) ? 256 : 512);
#pragma unroll
        for (int i = 0; i < 4; ++i) {
            int l = lbase + i;
            int r = l / HW, s = l % HW;
            int base = (r + 8) * HP + (s + 8);
#pragma unroll
            for (int j = 0; j < 4; ++j)
                dst[(cb + j) * HP2 + base] = acc[i][j] + bias[ocbase + j];
        }
    }
}

// one block per spatial position n; scrambled-window attention.
// Bijection: j = n1*256 + (h*32+cc) = c*289 + p. Lane t loads flat element
// j = n1*256 + t (coalesced runs of 17), logit[h=t/32][n1] = 32-lane group sum.
__global__ __launch_bounds__(256) void attn_kernel(const float* __restrict__ qbuf,
                                                   const float* __restrict__ kpad,
                                                   const float* __restrict__ vpad,
                                                   const int* __restrict__ addrtab,
                                                   float* __restrict__ abuf) {
    __shared__ float logit[HEADS][292];
    const int n = blockIdx.x;
    const int tid = threadIdx.x;
    const int nr = n / HW, ncl = n % HW;
    const int basen = nr * HP + ncl;  // top-left of window in padded coords

    const float qv = qbuf[n * C + tid];
    const float* kb = kpad + basen;
    const float* vb = vpad + basen;
    const int g = tid >> 5;          // head for this lane's segment

    // phase B: logits. One n1 per iteration; 256 lanes cover all 8 heads.
#pragma unroll 4
    for (int n1 = 0; n1 < K2; ++n1) {
        float e = qv * kb[addrtab[n1 * 256 + tid]];
#pragma unroll
        for (int off = 1; off <= 16; off <<= 1) e += __shfl_xor(e, off, 64);
        if ((tid & 31) == 0) logit[g][n1] = e;
    }
    __syncthreads();

    // phase C: softmax over n1 per head, then post-softmax validity mask
    {
        const int wave = tid >> 6, lane = tid & 63;
        for (int hh = wave * 2; hh <= wave * 2 + 1; ++hh) {
            float mx = -1e30f;
            for (int n1 = lane; n1 < K2; n1 += 64) mx = fmaxf(mx, logit[hh][n1]);
#pragma unroll
            for (int off = 32; off; off >>= 1) mx = fmaxf(mx, __shfl_xor(mx, off, 64));
            float s = 0.f;
            for (int n1 = lane; n1 < K2; n1 += 64) {
                float e = __expf(logit[hh][n1] - mx);
                logit[hh][n1] = e;
                s += e;
            }
#pragma unroll
            for (int off = 32; off; off >>= 1) s += __shfl_xor(s, off, 64);
            const float inv = 1.f / s;
            for (int n1 = lane; n1 < K2; n1 += 64) {
                int dr = n1 / KW, ds = n1 % KW;
                int rr = nr + dr - 8, ss = ncl + ds - 8;
                float m = (rr >= 0 && rr < HW && ss >= 0 && ss < HW) ? 1.f : 0.f;
                logit[hh][n1] *= inv * m;
            }
        }
    }
    __syncthreads();

    // phase D: PV. Thread t owns output channel m=t; register accumulate.
    {
        float acc = 0.f;
#pragma unroll 4
        for (int n1 = 0; n1 < K2; ++n1)
            acc = fmaf(logit[g][n1], vb[addrtab[n1 * 256 + tid]], acc);
        abuf[n * C + tid] = acc;
    }
}

// out[oc*1600 + l] = sum_c abuf[l, c] * w[oc, c] + b[oc]   (transposed store)
__global__ __launch_bounds__(256) void proj_gemm(const float* __restrict__ abuf,
                                                 const float* __restrict__ w,
                                                 const float* __restrict__ bias,
                                                 float* __restrict__ out) {
    __shared__ float As[16][68];  // A[c][l]
    __shared__ float Bs[16][68];  // B[c][oc]
    const int l0 = blockIdx.x * 64;
    const int oc0 = blockIdx.y * 64;
    const int tid = threadIdx.x;
    const int tx = tid & 15;   // l quad
    const int ty = tid >> 4;   // oc quad
    float acc[4][4] = {};      // [i: oc][j: l]
    for (int c0 = 0; c0 < C; c0 += 16) {
#pragma unroll
        for (int i = 0; i < 4; ++i) {
            int idx = i * 256 + tid;
            int cc = idx & 15, ll = idx >> 4;
            As[cc][ll] = abuf[(l0 + ll) * C + c0 + cc];
        }
#pragma unroll
        for (int i = 0; i < 4; ++i) {
            int idx = i * 256 + tid;
            int cc = idx & 15, oo = idx >> 4;
            Bs[cc][oo] = w[(oc0 + oo) * C + c0 + cc];
        }
        __syncthreads();
#pragma unroll
        for (int kk = 0; kk < 16; ++kk) {
            float4 a = *(const float4*)&As[kk][tx * 4];
            float4 b = *(const float4*)&Bs[kk][ty * 4];
            float av[4] = {a.x, a.y, a.z, a.w};
            float bv[4] = {b.x, b.y, b.z, b.w};
#pragma unroll
            for (int i = 0; i < 4; ++i)
#pragma unroll
                for (int j = 0; j < 4; ++j)
                    acc[i][j] = fmaf(bv[i], av[j], acc[i][j]);
        }
        __syncthreads();
    }
    const int lb = l0 + tx * 4;
#pragma unroll
    for (int i = 0; i < 4; ++i) {
        int oc = oc0 + ty * 4 + i;
        float bp = bias[oc];
        float4 v = make_float4(acc[i][0] + bp, acc[i][1] + bp,
                               acc[i][2] + bp, acc[i][3] + bp);
        *(float4*)&out[oc * L + lb] = v;
    }
}

extern "C" void kernel_launch(void* const* d_in, const int* in_sizes, int n_in,
                              void* d_out, int out_size, void* d_ws, size_t ws_size,
                              hipStream_t stream) {
    const float* x      = (const float*)d_in[0];
    const float* w_qkv  = (const float*)d_in[1];
    const float* b_qkv  = (const float*)d_in[2];
    const float* w_proj = (const float*)d_in[3];
    const float* b_proj = (const float*)d_in[4];
    float* out = (float*)d_out;
    float* ws = (float*)d_ws;
    float* qbuf = ws + OFF_Q;
    float* kpad = ws + OFF_K;
    float* vpad = ws + OFF_V;
    float* abuf = ws + OFF_A;
    int*   atab = (int*)(ws + OFF_T);

    // zero padded K/V images (both contiguous: 2 * 802816 floats)
    const int n4 = (2 * 802816) / 4;
    zero_kernel<<<n4 / 256, 256, 0, stream>>>((float4*)kpad, n4);
    addr_kernel<<<NJ / 256, 256, 0, stream>>>(atab);

    qkv_gemm<<<dim3(25, 12), 256, 0, stream>>>(x, w_qkv, b_qkv, qbuf, kpad, vpad);
    attn_kernel<<<1600, 256, 0, stream>>>(qbuf, kpad, vpad, atab, abuf);
    proj_gemm<<<dim3(25, 4), 256, 0, stream>>>(abuf, w_proj, b_proj, out);
}

// Round 3
// 172.700 us; speedup vs baseline: 3.3212x; 1.7530x over previous
//
#include <hip/hip_runtime.h>

#define L 1600
#define C 256
#define HW 40
#define HP 56            // padded spatial (40 + 2*8)
#define HP2 (HP * HP)    // 3136
#define KW 17
#define K2 289
#define HEADS 8
#define C1 32
#define SCALE 0.17677669529663687f  // 32^-0.5

// workspace layout (in floats)
#define OFF_Q 0
#define OFF_K 409600
#define OFF_V (409600 + 802816)
#define OFF_A (409600 + 2 * 802816)

__global__ __launch_bounds__(256) void zero_kernel(float4* __restrict__ p, int n4) {
    int i = blockIdx.x * 256 + threadIdx.x;
    if (i < n4) p[i] = make_float4(0.f, 0.f, 0.f, 0.f);
}

// qkv[l, oc] = sum_c x[c, l] * w[oc, c] + b[oc];  q scaled, k/v scattered into padded images
__global__ __launch_bounds__(256) void qkv_gemm(const float* __restrict__ x,
                                                const float* __restrict__ w,
                                                const float* __restrict__ bias,
                                                float* __restrict__ qbuf,
                                                float* __restrict__ kpad,
                                                float* __restrict__ vpad) {
    __shared__ float As[16][68];  // A[c][l]
    __shared__ float Bs[16][68];  // B[c][oc]
    const int l0 = blockIdx.x * 64;
    const int oc0 = blockIdx.y * 64;
    const int tid = threadIdx.x;
    const int tx = tid & 15;   // oc quad
    const int ty = tid >> 4;   // l quad
    float acc[4][4] = {};
    for (int c0 = 0; c0 < C; c0 += 16) {
#pragma unroll
        for (int i = 0; i < 4; ++i) {
            int idx = i * 256 + tid;
            int cc = idx >> 6, ll = idx & 63;
            As[cc][ll] = x[(c0 + cc) * L + l0 + ll];
        }
#pragma unroll
        for (int i = 0; i < 4; ++i) {
            int idx = i * 256 + tid;
            int cc = idx & 15, oo = idx >> 4;
            Bs[cc][oo] = w[(oc0 + oo) * C + c0 + cc];
        }
        __syncthreads();
#pragma unroll
        for (int kk = 0; kk < 16; ++kk) {
            float4 a = *(const float4*)&As[kk][ty * 4];
            float4 b = *(const float4*)&Bs[kk][tx * 4];
            float av[4] = {a.x, a.y, a.z, a.w};
            float bv[4] = {b.x, b.y, b.z, b.w};
#pragma unroll
            for (int i = 0; i < 4; ++i)
#pragma unroll
                for (int j = 0; j < 4; ++j)
                    acc[i][j] = fmaf(av[i], bv[j], acc[i][j]);
        }
        __syncthreads();
    }
    const int lbase = l0 + ty * 4;
    const int ocbase = oc0 + tx * 4;
    if (oc0 < 256) {
#pragma unroll
        for (int i = 0; i < 4; ++i) {
            float4 v;
            v.x = (acc[i][0] + bias[ocbase + 0]) * SCALE;
            v.y = (acc[i][1] + bias[ocbase + 1]) * SCALE;
            v.z = (acc[i][2] + bias[ocbase + 2]) * SCALE;
            v.w = (acc[i][3] + bias[ocbase + 3]) * SCALE;
            *(float4*)&qbuf[(lbase + i) * C + ocbase] = v;
        }
    } else {
        float* dst = (oc0 < 512) ? kpad : vpad;
        const int cb = ocbase - ((oc0 < 512) ? 256 : 512);
#pragma unroll
        for (int i = 0; i < 4; ++i) {
            int l = lbase + i;
            int r = l / HW, s = l % HW;
            int base = (r + 8) * HP + (s + 8);
#pragma unroll
            for (int j = 0; j < 4; ++j)
                dst[(cb + j) * HP2 + base] = acc[i][j] + bias[ocbase + j];
        }
    }
}

// one block per spatial position n; scrambled-window attention.
// Bijection: j = n1*256 + (h*32+cc) = c*289 + p. Lane t handles flat element
// j = n1*256 + t (coalesced runs of 17). (c,p) tracked incrementally:
// j += 256  =>  p -= 33 (c += 1), or p += 256 (c same) when p < 33.
__global__ __launch_bounds__(256) void attn_kernel(const float* __restrict__ qbuf,
                                                   const float* __restrict__ kpad,
                                                   const float* __restrict__ vpad,
                                                   float* __restrict__ abuf) {
    __shared__ float logit[HEADS][292];
    __shared__ int woff[K2];
    const int n = blockIdx.x;
    const int tid = threadIdx.x;
    const int nr = n / HW, ncl = n % HW;
    const int basen = nr * HP + ncl;  // top-left of window in padded coords

    for (int p = tid; p < K2; p += 256) {
        int dr = p / KW;
        woff[p] = dr * HP + (p - dr * KW);
    }
    const float qv = qbuf[n * C + tid];
    const float* kb = kpad + basen;
    const float* vb = vpad + basen;
    const int g = tid >> 5;          // head for this lane's group
    __syncthreads();

    // phase B: logits. 4 n1 per step with merged butterfly reduction.
    {
        int p = tid;                  // n1=0: j=tid<289 -> c=0, p=tid
        const float* kc = kb;
        int i4 = 0;
#pragma unroll 2
        for (int i = 0; i < 72; ++i) {
            float e0, e1, e2, e3;
            e0 = qv * kc[woff[p]];
            p -= 33; if (p < 0) p += 289; else kc += HP2;
            e1 = qv * kc[woff[p]];
            p -= 33; if (p < 0) p += 289; else kc += HP2;
            e2 = qv * kc[woff[p]];
            p -= 33; if (p < 0) p += 289; else kc += HP2;
            e3 = qv * kc[woff[p]];
            p -= 33; if (p < 0) p += 289; else kc += HP2;

            float a0 = e0 + __shfl_xor(e0, 1, 64);
            float a1 = e1 + __shfl_xor(e1, 1, 64);
            float a2 = e2 + __shfl_xor(e2, 1, 64);
            float a3 = e3 + __shfl_xor(e3, 1, 64);
            float b0 = (tid & 1) ? a1 : a0;
            float b1 = (tid & 1) ? a3 : a2;
            b0 += __shfl_xor(b0, 2, 64);
            b1 += __shfl_xor(b1, 2, 64);
            float c0 = (tid & 2) ? b1 : b0;
            c0 += __shfl_xor(c0, 4, 64);
            c0 += __shfl_xor(c0, 8, 64);
            c0 += __shfl_xor(c0, 16, 64);
            if ((tid & 31) < 4) logit[g][i4 + (tid & 31)] = c0;
            i4 += 4;
        }
        // tail n1 = 288
        float e = qv * kc[woff[p]];
#pragma unroll
        for (int off = 1; off <= 16; off <<= 1) e += __shfl_xor(e, off, 64);
        if ((tid & 31) == 0) logit[g][288] = e;
    }
    __syncthreads();

    // phase C: softmax over n1 per head, then post-softmax validity mask
    {
        const int wave = tid >> 6, lane = tid & 63;
        for (int hh = wave * 2; hh <= wave * 2 + 1; ++hh) {
            float mx = -1e30f;
            for (int n1 = lane; n1 < K2; n1 += 64) mx = fmaxf(mx, logit[hh][n1]);
#pragma unroll
            for (int off = 32; off; off >>= 1) mx = fmaxf(mx, __shfl_xor(mx, off, 64));
            float s = 0.f;
            for (int n1 = lane; n1 < K2; n1 += 64) {
                float e = __expf(logit[hh][n1] - mx);
                logit[hh][n1] = e;
                s += e;
            }
#pragma unroll
            for (int off = 32; off; off >>= 1) s += __shfl_xor(s, off, 64);
            const float inv = 1.f / s;
            for (int n1 = lane; n1 < K2; n1 += 64) {
                int dr = n1 / KW, ds = n1 % KW;
                int rr = nr + dr - 8, ss = ncl + ds - 8;
                float m = (rr >= 0 && rr < HW && ss >= 0 && ss < HW) ? 1.f : 0.f;
                logit[hh][n1] *= inv * m;
            }
        }
    }
    __syncthreads();

    // phase D: PV. Thread t owns output channel m=t; register accumulate.
    {
        int p = tid;
        const float* vc = vb;
        float acc = 0.f;
#pragma unroll 4
        for (int n1 = 0; n1 < K2; ++n1) {
            acc = fmaf(logit[g][n1], vc[woff[p]], acc);
            p -= 33; if (p < 0) p += 289; else vc += HP2;
        }
        abuf[n * C + tid] = acc;
    }
}

// out[oc*1600 + l] = sum_c abuf[l, c] * w[oc, c] + b[oc]   (transposed store)
__global__ __launch_bounds__(256) void proj_gemm(const float* __restrict__ abuf,
                                                 const float* __restrict__ w,
                                                 const float* __restrict__ bias,
                                                 float* __restrict__ out) {
    __shared__ float As[16][68];  // A[c][l]
    __shared__ float Bs[16][68];  // B[c][oc]
    const int l0 = blockIdx.x * 64;
    const int oc0 = blockIdx.y * 64;
    const int tid = threadIdx.x;
    const int tx = tid & 15;   // l quad
    const int ty = tid >> 4;   // oc quad
    float acc[4][4] = {};      // [i: oc][j: l]
    for (int c0 = 0; c0 < C; c0 += 16) {
#pragma unroll
        for (int i = 0; i < 4; ++i) {
            int idx = i * 256 + tid;
            int cc = idx & 15, ll = idx >> 4;
            As[cc][ll] = abuf[(l0 + ll) * C + c0 + cc];
        }
#pragma unroll
        for (int i = 0; i < 4; ++i) {
            int idx = i * 256 + tid;
            int cc = idx & 15, oo = idx >> 4;
            Bs[cc][oo] = w[(oc0 + oo) * C + c0 + cc];
        }
        __syncthreads();
#pragma unroll
        for (int kk = 0; kk < 16; ++kk) {
            float4 a = *(const float4*)&As[kk][tx * 4];
            float4 b = *(const float4*)&Bs[kk][ty * 4];
            float av[4] = {a.x, a.y, a.z, a.w};
            float bv[4] = {b.x, b.y, b.z, b.w};
#pragma unroll
            for (int i = 0; i < 4; ++i)
#pragma unroll
                for (int j = 0; j < 4; ++j)
                    acc[i][j] = fmaf(bv[i], av[j], acc[i][j]);
        }
        __syncthreads();
    }
    const int lb = l0 + tx * 4;
#pragma unroll
    for (int i = 0; i < 4; ++i) {
        int oc = oc0 + ty * 4 + i;
        float bp = bias[oc];
        float4 v = make_float4(acc[i][0] + bp, acc[i][1] + bp,
                               acc[i][2] + bp, acc[i][3] + bp);
        *(float4*)&out[oc * L + lb] = v;
    }
}

extern "C" void kernel_launch(void* const* d_in, const int* in_sizes, int n_in,
                              void* d_out, int out_size, void* d_ws, size_t ws_size,
                              hipStream_t stream) {
    const float* x      = (const float*)d_in[0];
    const float* w_qkv  = (const float*)d_in[1];
    const float* b_qkv  = (const float*)d_in[2];
    const float* w_proj = (const float*)d_in[3];
    const float* b_proj = (const float*)d_in[4];
    float* out = (float*)d_out;
    float* ws = (float*)d_ws;
    float* qbuf = ws + OFF_Q;
    float* kpad = ws + OFF_K;
    float* vpad = ws + OFF_V;
    float* abuf = ws + OFF_A;

    // zero padded K/V images (both contiguous: 2 * 802816 floats)
    const int n4 = (2 * 802816) / 4;
    zero_kernel<<<n4 / 256, 256, 0, stream>>>((float4*)kpad, n4);

    qkv_gemm<<<dim3(25, 12), 256, 0, stream>>>(x, w_qkv, b_qkv, qbuf, kpad, vpad);
    attn_kernel<<<1600, 256, 0, stream>>>(qbuf, kpad, vpad, abuf);
    proj_gemm<<<dim3(25, 4), 256, 0, stream>>>(abuf, w_proj, b_proj, out);
}

// Round 4
// 154.638 us; speedup vs baseline: 3.7091x; 1.1168x over previous
//
#include <hip/hip_runtime.h>

#define L 1600
#define C 256
#define HW 40
#define HP 56            // padded spatial (40 + 2*8)
#define HP2 (HP * HP)    // 3136
#define KW 17
#define K2 289
#define HEADS 8
#define NJ (K2 * 256)    // 73984 flat window elements
#define NBINS (K2 * 8)   // 2312
#define SCALE 0.17677669529663687f  // 32^-0.5

// workspace layout (in floats); qT is reused as outT (disjoint lifetimes)
#define OFF_TAB   0
#define OFF_TABD  (OFF_TAB + NJ)
#define OFF_INV   (OFF_TABD + NJ)
#define OFF_QT    (OFF_INV + HEADS * L)
#define OFF_K     (OFF_QT + 409600)
#define OFF_V     (OFF_K + 802816)
#define OFF_P     (OFF_V + 802816)
// total = 2*73984 + 12800 + 409600 + 2*802816 + 2312*1600 = 5,875,200 floats (23.5 MB)

__global__ __launch_bounds__(256) void zero_kernel(float4* __restrict__ p, int n4) {
    int i = blockIdx.x * 256 + threadIdx.x;
    if (i < n4) p[i] = make_float4(0.f, 0.f, 0.f, 0.f);
}

// offtab[j]  = image offset of flat-window element j (j = c*289 + p)
// offtabD[m*289 + n1] = offtab[n1*256 + m]   (phase-D access order)
__global__ __launch_bounds__(256) void addr_kernel(int* __restrict__ offtab,
                                                   int* __restrict__ offtabD) {
    int j = blockIdx.x * 256 + threadIdx.x;   // grid covers exactly NJ
    int c = j / K2;
    int p = j - c * K2;
    int dr = p / KW;
    int ds = p - dr * KW;
    int off = c * HP2 + dr * HP + ds;
    offtab[j] = off;
    int n1 = j >> 8, m = j & 255;
    offtabD[m * K2 + n1] = off;
}

// qkv[l, oc] = sum_c x[c, l] * w[oc, c] + b[oc]
// q (scaled) -> qT[m][l];  k/v -> padded images
__global__ __launch_bounds__(256) void qkv_gemm(const float* __restrict__ x,
                                                const float* __restrict__ w,
                                                const float* __restrict__ bias,
                                                float* __restrict__ qT,
                                                float* __restrict__ kpad,
                                                float* __restrict__ vpad) {
    __shared__ float As[16][68];  // A[c][l]
    __shared__ float Bs[16][68];  // B[c][oc]
    const int l0 = blockIdx.x * 64;
    const int oc0 = blockIdx.y * 64;
    const int tid = threadIdx.x;
    const int tx = tid & 15;   // oc quad
    const int ty = tid >> 4;   // l quad
    float acc[4][4] = {};
    for (int c0 = 0; c0 < C; c0 += 16) {
#pragma unroll
        for (int i = 0; i < 4; ++i) {
            int idx = i * 256 + tid;
            int cc = idx >> 6, ll = idx & 63;
            As[cc][ll] = x[(c0 + cc) * L + l0 + ll];
        }
#pragma unroll
        for (int i = 0; i < 4; ++i) {
            int idx = i * 256 + tid;
            int cc = idx & 15, oo = idx >> 4;
            Bs[cc][oo] = w[(oc0 + oo) * C + c0 + cc];
        }
        __syncthreads();
#pragma unroll
        for (int kk = 0; kk < 16; ++kk) {
            float4 a = *(const float4*)&As[kk][ty * 4];
            float4 b = *(const float4*)&Bs[kk][tx * 4];
            float av[4] = {a.x, a.y, a.z, a.w};
            float bv[4] = {b.x, b.y, b.z, b.w};
#pragma unroll
            for (int i = 0; i < 4; ++i)
#pragma unroll
                for (int j = 0; j < 4; ++j)
                    acc[i][j] = fmaf(av[i], bv[j], acc[i][j]);
        }
        __syncthreads();
    }
    const int lbase = l0 + ty * 4;
    const int ocbase = oc0 + tx * 4;
    if (oc0 < 256) {
#pragma unroll
        for (int j = 0; j < 4; ++j) {
            int oc = ocbase + j;
            float b = bias[oc];
            float4 v = make_float4((acc[0][j] + b) * SCALE, (acc[1][j] + b) * SCALE,
                                   (acc[2][j] + b) * SCALE, (acc[3][j] + b) * SCALE);
            *(float4*)&qT[oc * L + lbase] = v;
        }
    } else {
        float* dst = (oc0 < 512) ? kpad : vpad;
        const int cb = ocbase - ((oc0 < 512) ? 256 : 512);
#pragma unroll
        for (int i = 0; i < 4; ++i) {
            int l = lbase + i;
            int r = l / HW, s = l % HW;
            int base = (r + 8) * HP + (s + 8);
#pragma unroll
            for (int j = 0; j < 4; ++j)
                dst[(cb + j) * HP2 + base] = acc[i][j] + bias[ocbase + j];
        }
    }
}

// Phase B: logits. Block-uniform (h, n1-chunk); lanes = n. Gather offsets are
// scalar (offtab, uniform index); q in 32 regs reused across the chunk;
// K loads coalesced over consecutive n. P[n1*8+h][n] = <q, K_window>.
__global__ __launch_bounds__(256) void attnB(const float* __restrict__ qT,
                                             const float* __restrict__ kpad,
                                             const int* __restrict__ offtab,
                                             float* __restrict__ P) {
    const int h = blockIdx.y;
    const int n = blockIdx.z * 256 + threadIdx.x;
    const bool valid = (n < L);
    const int nn = valid ? n : 0;
    const int basen = (nn / HW) * HP + (nn % HW);
    float q[32];
#pragma unroll
    for (int k = 0; k < 32; ++k) q[k] = qT[(h * 32 + k) * L + nn];
    const float* kb = kpad + basen;
    int n1 = blockIdx.x * 17;
    for (int b = 0; b < 17; ++b, ++n1) {
        const int j0 = n1 * 256 + h * 32;   // uniform
        float acc = 0.f;
#pragma unroll
        for (int k = 0; k < 32; ++k)
            acc = fmaf(q[k], kb[offtab[j0 + k]], acc);
        if (valid) P[(n1 * 8 + h) * L + n] = acc;
    }
}

// Phase C: per (n, h): max over n1, P := exp(x-max)*mask (UN-normalized),
// inv[h][n] = 1/sum(exp) (sum over ALL slots, pre-mask, as in reference).
__global__ __launch_bounds__(256) void attnC(float* __restrict__ P,
                                             float* __restrict__ inv) {
    __shared__ float red[4][64];
    const int t = threadIdx.x;
    const int h = blockIdx.y;
    const int nl = t & 63;
    const int n = blockIdx.x * 64 + nl;
    const int qtr = t >> 6;
    const int n1lo = qtr * 73;
    const int n1hi = (n1lo + 73 < K2) ? n1lo + 73 : K2;
    const int nr = n / HW, nc = n % HW;
    float mx = -1e30f;
    for (int n1 = n1lo; n1 < n1hi; ++n1)
        mx = fmaxf(mx, P[(n1 * 8 + h) * L + n]);
    red[qtr][nl] = mx;
    __syncthreads();
    mx = fmaxf(fmaxf(red[0][nl], red[1][nl]), fmaxf(red[2][nl], red[3][nl]));
    __syncthreads();
    float s = 0.f;
    for (int n1 = n1lo; n1 < n1hi; ++n1) {
        float v = P[(n1 * 8 + h) * L + n];
        float e = __expf(v - mx);
        s += e;
        int dr = n1 / KW, ds = n1 - dr * KW;       // uniform per iter
        unsigned rr = (unsigned)(nr + dr - 8), ss = (unsigned)(nc + ds - 8);
        float msk = (rr < HW && ss < HW) ? 1.f : 0.f;
        P[(n1 * 8 + h) * L + n] = e * msk;
    }
    red[qtr][nl] = s;
    __syncthreads();
    if (qtr == 0)
        inv[h * L + n] = 1.f / (red[0][nl] + red[1][nl] + red[2][nl] + red[3][nl]);
}

// Phase D: out2T[m][n] = inv[h][n] * sum_n1 P[n1*8+h][n] * V_window.
// Block-uniform m; scalar offsets via offtabD; coalesced over n.
__global__ __launch_bounds__(256) void attnD(const float* __restrict__ P,
                                             const float* __restrict__ vpad,
                                             const int* __restrict__ offtabD,
                                             const float* __restrict__ inv,
                                             float* __restrict__ outT) {
    const int m = blockIdx.x;
    const int h = m >> 5;
    const int n = blockIdx.y * 256 + threadIdx.x;
    const bool valid = (n < L);
    const int nn = valid ? n : 0;
    const int basen = (nn / HW) * HP + (nn % HW);
    const float* vb = vpad + basen;
    const int* tb = offtabD + m * K2;
    float acc = 0.f;
#pragma unroll 17
    for (int n1 = 0; n1 < K2; ++n1)
        acc = fmaf(P[(n1 * 8 + h) * L + nn], vb[tb[n1]], acc);
    if (valid) outT[m * L + n] = acc * inv[h * L + nn];
}

// out[oc*1600 + l] = sum_c outT[c][l] * w[oc, c] + b[oc]
__global__ __launch_bounds__(256) void proj_gemm(const float* __restrict__ aT,
                                                 const float* __restrict__ w,
                                                 const float* __restrict__ bias,
                                                 float* __restrict__ out) {
    __shared__ float As[16][68];  // A[c][l]
    __shared__ float Bs[16][68];  // B[c][oc]
    const int l0 = blockIdx.x * 64;
    const int oc0 = blockIdx.y * 64;
    const int tid = threadIdx.x;
    const int tx = tid & 15;   // oc quad
    const int ty = tid >> 4;   // l quad
    float acc[4][4] = {};      // [i: l][j: oc]
    for (int c0 = 0; c0 < C; c0 += 16) {
#pragma unroll
        for (int i = 0; i < 4; ++i) {
            int idx = i * 256 + tid;
            int cc = idx >> 6, ll = idx & 63;
            As[cc][ll] = aT[(c0 + cc) * L + l0 + ll];
        }
#pragma unroll
        for (int i = 0; i < 4; ++i) {
            int idx = i * 256 + tid;
            int cc = idx & 15, oo = idx >> 4;
            Bs[cc][oo] = w[(oc0 + oo) * C + c0 + cc];
        }
        __syncthreads();
#pragma unroll
        for (int kk = 0; kk < 16; ++kk) {
            float4 a = *(const float4*)&As[kk][ty * 4];
            float4 b = *(const float4*)&Bs[kk][tx * 4];
            float av[4] = {a.x, a.y, a.z, a.w};
            float bv[4] = {b.x, b.y, b.z, b.w};
#pragma unroll
            for (int i = 0; i < 4; ++i)
#pragma unroll
                for (int j = 0; j < 4; ++j)
                    acc[i][j] = fmaf(av[i], bv[j], acc[i][j]);
        }
        __syncthreads();
    }
    const int lbase = l0 + ty * 4;
#pragma unroll
    for (int j = 0; j < 4; ++j) {
        int oc = oc0 + tx * 4 + j;
        float bp = bias[oc];
        float4 v = make_float4(acc[0][j] + bp, acc[1][j] + bp,
                               acc[2][j] + bp, acc[3][j] + bp);
        *(float4*)&out[oc * L + lbase] = v;
    }
}

extern "C" void kernel_launch(void* const* d_in, const int* in_sizes, int n_in,
                              void* d_out, int out_size, void* d_ws, size_t ws_size,
                              hipStream_t stream) {
    const float* x      = (const float*)d_in[0];
    const float* w_qkv  = (const float*)d_in[1];
    const float* b_qkv  = (const float*)d_in[2];
    const float* w_proj = (const float*)d_in[3];
    const float* b_proj = (const float*)d_in[4];
    float* out = (float*)d_out;
    float* ws = (float*)d_ws;
    int*   offtab  = (int*)(ws + OFF_TAB);
    int*   offtabD = (int*)(ws + OFF_TABD);
    float* inv  = ws + OFF_INV;
    float* qT   = ws + OFF_QT;   // reused as outT after attnB finishes
    float* kpad = ws + OFF_K;
    float* vpad = ws + OFF_V;
    float* P    = ws + OFF_P;

    // zero padded K/V images (contiguous: 2 * 802816 floats)
    const int n4 = (2 * 802816) / 4;
    zero_kernel<<<n4 / 256, 256, 0, stream>>>((float4*)kpad, n4);
    addr_kernel<<<NJ / 256, 256, 0, stream>>>(offtab, offtabD);

    qkv_gemm<<<dim3(25, 12), 256, 0, stream>>>(x, w_qkv, b_qkv, qT, kpad, vpad);
    attnB<<<dim3(17, 8, 7), 256, 0, stream>>>(qT, kpad, offtab, P);
    attnC<<<dim3(25, 8), 256, 0, stream>>>(P, inv);
    attnD<<<dim3(256, 7), 256, 0, stream>>>(P, vpad, offtabD, inv, qT);
    proj_gemm<<<dim3(25, 4), 256, 0, stream>>>(qT, w_proj, b_proj, out);
}